// Round 4
// baseline (379.000 us; speedup 1.0000x reference)
//
#include <hip/hip_runtime.h>
#include <cstddef>

namespace {

constexpr int N  = 50000;   // nodes
constexpr int E  = 800000;  // edges
constexpr int DH = 64;      // hidden dim (layer1 out, layer2 in)
constexpr int DO = 32;      // output dim

// ---------------------------------------------------------------------------
// init: deg = 1.0 (self loop), zero agg1 and out accumulator.
// Must run every launch: harness poisons ws/out with 0xAA and never re-zeroes.
__global__ void k_init(float* __restrict__ deg, float* __restrict__ agg1,
                       float* __restrict__ out) {
    int i = blockIdx.x * blockDim.x + threadIdx.x;
    int stride = gridDim.x * blockDim.x;
    for (int j = i; j < N; j += stride) deg[j] = 1.0f;
    for (int j = i; j < N * DH; j += stride) agg1[j] = 0.0f;
    for (int j = i; j < N * DO; j += stride) out[j] = 0.0f;
}

// in-degree via dst
__global__ void k_count(const int* __restrict__ dst, float* __restrict__ deg) {
    int e = blockIdx.x * blockDim.x + threadIdx.x;
    if (e < E) atomicAdd(&deg[dst[e]], 1.0f);
}

__global__ void k_dinv(const float* __restrict__ deg, float* __restrict__ dinv) {
    int i = blockIdx.x * blockDim.x + threadIdx.x;
    if (i < N) dinv[i] = rsqrtf(deg[i]);
}

// ---------------------------------------------------------------------------
// H[N,DOUT] = X[N,64] @ W[64,DOUT].  Block = 256 threads, 64 rows per block.
// W staged in LDS once per block (64*DOUT*4 B <= 16 KB).
template <int DOUT>
__global__ void k_gemm(const float* __restrict__ X, const float* __restrict__ W,
                       float* __restrict__ H) {
    __shared__ float Ws[64 * DOUT];
    const int tid = threadIdx.x;
    for (int i = tid; i < 64 * DOUT; i += 256) Ws[i] = W[i];
    __syncthreads();

    constexpr int RPI = 256 / DOUT;  // rows per iteration (4 or 8)
    const int col  = tid % DOUT;
    const int rsub = tid / DOUT;
    const int rowBase = blockIdx.x * 64;

    for (int r0 = 0; r0 < 64; r0 += RPI) {
        const int row = rowBase + r0 + rsub;
        if (row < N) {
            const float4* xr4 = reinterpret_cast<const float4*>(X + (size_t)row * 64);
            float acc = 0.0f;
#pragma unroll
            for (int k4 = 0; k4 < 16; ++k4) {
                float4 xv = xr4[k4];
                acc += xv.x * Ws[(4 * k4 + 0) * DOUT + col];
                acc += xv.y * Ws[(4 * k4 + 1) * DOUT + col];
                acc += xv.z * Ws[(4 * k4 + 2) * DOUT + col];
                acc += xv.w * Ws[(4 * k4 + 3) * DOUT + col];
            }
            H[(size_t)row * DOUT + col] = acc;
        }
    }
}

// ---------------------------------------------------------------------------
// AGG[dst] += H[src] * (dinv[src]*dinv[dst])  — one thread per (edge, feature).
// D is a power of two so e/f are shifts; each wave covers whole edges ->
// wave-(or half-wave-)uniform src/dst loads, coalesced gather + atomic scatter.
template <int D>
__global__ void k_scatter(const int* __restrict__ src, const int* __restrict__ dst,
                          const float* __restrict__ dinv, const float* __restrict__ H,
                          float* __restrict__ AGG) {
    const long long idx = (long long)blockIdx.x * blockDim.x + threadIdx.x;
    if (idx >= (long long)E * D) return;
    const int e = (int)(idx >> (D == 64 ? 6 : 5));
    const int f = (int)(idx & (D - 1));
    const int s = src[e];
    const int d = dst[e];
    const float nrm = dinv[s] * dinv[d];
    atomicAdd(&AGG[(size_t)d * D + f], H[(size_t)s * D + f] * nrm);
}

// ---------------------------------------------------------------------------
// Y = AGG + H * dinv^2[row] + b[col], optional ReLU.  In-place (Y == AGG) safe.
template <int D, bool RELU>
__global__ void k_post(const float* __restrict__ AGG, const float* __restrict__ H,
                       const float* __restrict__ dinv, const float* __restrict__ B,
                       float* __restrict__ Y) {
    const int i = blockIdx.x * blockDim.x + threadIdx.x;
    if (i >= N * D) return;
    const int row = i / D;
    const int f   = i % D;
    const float di = dinv[row];
    float v = AGG[i] + H[i] * di * di + B[f];
    if (RELU) v = fmaxf(v, 0.0f);
    Y[i] = v;
}

}  // namespace

extern "C" void kernel_launch(void* const* d_in, const int* in_sizes, int n_in,
                              void* d_out, int out_size, void* d_ws, size_t ws_size,
                              hipStream_t stream) {
    const float* x   = (const float*)d_in[0];
    // edge_index: [2, E]. Harness contract: integer inputs -> const int*.
    // npz-size forensics (round 0): x is f32 (12.8 MB), output f32 (5.9 MB
    // compressed) -> float* casts below are right.
    const int*   ei  = (const int*)d_in[1];   // row0 = src, row1 = dst
    const float* W1  = (const float*)d_in[2];
    const float* b1  = (const float*)d_in[3];
    const float* W2  = (const float*)d_in[4];
    const float* b2  = (const float*)d_in[5];
    float* out = (float*)d_out;

    const int* src = ei;
    const int* dst = ei + E;

    // workspace layout (floats)
    float* ws   = (float*)d_ws;
    float* deg  = ws;                  // N
    float* dinv = deg + N;             // N
    float* h1   = dinv + N;            // N*64   (reused for h2: N*32)
    float* agg1 = h1 + (size_t)N * DH; // N*64   (becomes y1 = relu(...) in place)
    float* h2   = h1;                  // h1 dead after post1

    // 1. init (deg=1, agg1=0, out=0)
    hipLaunchKernelGGL(k_init, dim3(2048), dim3(256), 0, stream, deg, agg1, out);
    // 2. degree count
    hipLaunchKernelGGL(k_count, dim3((E + 255) / 256), dim3(256), 0, stream, dst, deg);
    // 3. dinv = rsqrt(deg)
    hipLaunchKernelGGL(k_dinv, dim3((N + 255) / 256), dim3(256), 0, stream, deg, dinv);
    // 4. h1 = x @ W1
    hipLaunchKernelGGL((k_gemm<DH>), dim3((N + 63) / 64), dim3(256), 0, stream, x, W1, h1);
    // 5. agg1[dst] += h1[src] * norm
    hipLaunchKernelGGL((k_scatter<DH>), dim3((int)(((long long)E * DH + 255) / 256)),
                       dim3(256), 0, stream, src, dst, dinv, h1, agg1);
    // 6. y1 = relu(agg1 + h1*dinv^2 + b1)   (in place in agg1)
    hipLaunchKernelGGL((k_post<DH, true>), dim3((N * DH + 255) / 256), dim3(256), 0,
                       stream, agg1, h1, dinv, b1, agg1);
    // 7. h2 = y1 @ W2
    hipLaunchKernelGGL((k_gemm<DO>), dim3((N + 63) / 64), dim3(256), 0, stream, agg1, W2, h2);
    // 8. out[dst] += h2[src] * norm   (out pre-zeroed)
    hipLaunchKernelGGL((k_scatter<DO>), dim3((int)(((long long)E * DO + 255) / 256)),
                       dim3(256), 0, stream, src, dst, dinv, h2, out);
    // 9. out = out + h2*dinv^2 + b2   (in place)
    hipLaunchKernelGGL((k_post<DO, false>), dim3((N * DO + 255) / 256), dim3(256), 0,
                       stream, out, h2, dinv, b2, out);
}

// Round 7
// 355.989 us; speedup vs baseline: 1.0646x; 1.0646x over previous
//
#include <hip/hip_runtime.h>
#include <hip/hip_fp16.h>
#include <cstddef>
#include <cstdint>

namespace {

constexpr int N  = 50000;   // nodes  (must fit u16 for edge packing)
constexpr int E  = 800000;  // edges
constexpr int DH = 64;      // hidden dim
constexpr int DO = 32;      // output dim
static_assert(N < 65536, "src packed as u16");

__device__ inline float bf2f(uint16_t u) {
    union { uint32_t u; float f; } c; c.u = (uint32_t)u << 16; return c.f;
}
__device__ inline uint16_t f2bf(float f) {   // RTNE
    union { float f; uint32_t u; } c; c.f = f;
    uint32_t r = c.u + 0x7FFFu + ((c.u >> 16) & 1u);
    return (uint16_t)(r >> 16);
}

// ---------------------------------------------------------------------------
// zero the dst histogram (ws is poisoned 0xAA; must re-zero every launch)
__global__ void k_zero(int* __restrict__ cnt) {
    int i = blockIdx.x * blockDim.x + threadIdx.x;
    if (i < N) cnt[i] = 0;
}

// in-degree histogram (int atomics)
__global__ void k_count(const int* __restrict__ dst, int* __restrict__ cnt) {
    int e = blockIdx.x * blockDim.x + threadIdx.x;
    if (e < E) atomicAdd(&cnt[dst[e]], 1);
}

// single-block fused: exclusive scan of cnt -> rowptr, cursor copy,
// dinv = rsqrt(cnt+1). 1024 threads, each owns a contiguous chunk.
__global__ __launch_bounds__(1024) void k_scan(const int* __restrict__ cnt,
                                               int* __restrict__ rowptr,
                                               int* __restrict__ cursor,
                                               float* __restrict__ dinv) {
    __shared__ int ts[1024];
    const int t = threadIdx.x;
    constexpr int CH = (N + 1023) / 1024;          // 49
    const int b = t * CH, e = min(b + CH, N);
    int s = 0;
    for (int i = b; i < e; ++i) s += cnt[i];
    ts[t] = s;
    __syncthreads();
    // Hillis-Steele inclusive scan over 1024 thread sums
    for (int off = 1; off < 1024; off <<= 1) {
        int v = (t >= off) ? ts[t - off] : 0;
        __syncthreads();
        ts[t] += v;
        __syncthreads();
    }
    int run = (t == 0) ? 0 : ts[t - 1];            // exclusive base
    for (int i = b; i < e; ++i) {
        rowptr[i] = run;
        cursor[i] = run;
        dinv[i]   = rsqrtf((float)(cnt[i] + 1));
        run += cnt[i];
    }
    if (t == 1023) rowptr[N] = run;                // == E
}

// scatter edges into CSR slots; pack (src u16 | wnorm f16 << 16)
__global__ void k_fill(const int* __restrict__ src, const int* __restrict__ dst,
                       const float* __restrict__ dinv, int* __restrict__ cursor,
                       uint32_t* __restrict__ epack) {
    int e = blockIdx.x * blockDim.x + threadIdx.x;
    if (e >= E) return;
    const int s = src[e], d = dst[e];
    const float wn = dinv[s] * dinv[d];
    const int pos = atomicAdd(&cursor[d], 1);
    const uint16_t hb = __half_as_ushort(__float2half(wn));
    epack[pos] = (uint32_t)s | ((uint32_t)hb << 16);
}

// ---------------------------------------------------------------------------
// H[N,DOUT] = X[N,64] @ W[64,DOUT]; W staged in LDS. OutT = ushort(bf16)|float.
template <int DOUT, typename OutT>
__global__ void k_gemm(const float* __restrict__ X, const float* __restrict__ W,
                       OutT* __restrict__ H) {
    __shared__ float Ws[64 * DOUT];
    const int tid = threadIdx.x;
    for (int i = tid; i < 64 * DOUT; i += 256) Ws[i] = W[i];
    __syncthreads();

    constexpr int RPI = 256 / DOUT;
    const int col  = tid % DOUT;
    const int rsub = tid / DOUT;
    const int rowBase = blockIdx.x * 64;

    for (int r0 = 0; r0 < 64; r0 += RPI) {
        const int row = rowBase + r0 + rsub;
        if (row < N) {
            const float4* xr4 = reinterpret_cast<const float4*>(X + (size_t)row * 64);
            float acc = 0.0f;
#pragma unroll
            for (int k4 = 0; k4 < 16; ++k4) {
                float4 xv = xr4[k4];
                acc += xv.x * Ws[(4 * k4 + 0) * DOUT + col];
                acc += xv.y * Ws[(4 * k4 + 1) * DOUT + col];
                acc += xv.z * Ws[(4 * k4 + 2) * DOUT + col];
                acc += xv.w * Ws[(4 * k4 + 3) * DOUT + col];
            }
            if constexpr (sizeof(OutT) == 2)
                H[(size_t)row * DOUT + col] = f2bf(acc);
            else
                H[(size_t)row * DOUT + col] = acc;
        }
    }
}

// ---------------------------------------------------------------------------
// Layer-1 aggregation, one wave per node, lane = feature (D=64).
// y1[n] = relu( sum_j wn_j * h1[src_j] + dinv[n]^2 * h1[n] + b1 )
__global__ void k_agg1(const int* __restrict__ rowptr, const uint32_t* __restrict__ epack,
                       const uint16_t* __restrict__ h1, const float* __restrict__ dinv,
                       const float* __restrict__ b1, float* __restrict__ y1) {
    const int gtid = blockIdx.x * blockDim.x + threadIdx.x;
    const int n    = gtid >> 6;
    const int lane = gtid & 63;
    if (n >= N) return;
    const int beg = rowptr[n], end = rowptr[n + 1];
    float acc = 0.0f;
#pragma unroll 4
    for (int j = beg; j < end; ++j) {
        const uint32_t w = epack[j];                       // wave-uniform, L1-hot
        const int   s  = (int)(w & 0xFFFFu);
        const float wn = __half2float(__ushort_as_half((uint16_t)(w >> 16)));
        acc += wn * bf2f(h1[(size_t)s * DH + lane]);       // 128B coalesced gather
    }
    const float di   = dinv[n];
    const float self = bf2f(h1[(size_t)n * DH + lane]);
    const float v    = acc + self * di * di + b1[lane];
    y1[(size_t)n * DH + lane] = fmaxf(v, 0.0f);
}

// Layer-2 aggregation, one wave per node, two edges per iteration:
// lanes [0,32) handle edge j, lanes [32,64) handle edge j+1; halves summed at end.
// out[n] = sum_j wn_j * h2[src_j] + dinv[n]^2 * h2[n] + b2
__global__ void k_agg2(const int* __restrict__ rowptr, const uint32_t* __restrict__ epack,
                       const float* __restrict__ h2, const float* __restrict__ dinv,
                       const float* __restrict__ b2, float* __restrict__ out) {
    const int gtid = blockIdx.x * blockDim.x + threadIdx.x;
    const int n    = gtid >> 6;
    const int lane = gtid & 63;
    if (n >= N) return;
    const int h = lane >> 5;          // 0 or 1: which edge of the pair
    const int f = lane & 31;          // feature
    const int beg = rowptr[n], end = rowptr[n + 1];
    float acc = 0.0f;
    int j = beg;
    for (; j + 1 < end; j += 2) {
        const uint32_t w = epack[j + h];
        const int   s  = (int)(w & 0xFFFFu);
        const float wn = __half2float(__ushort_as_half((uint16_t)(w >> 16)));
        acc += wn * h2[(size_t)s * DO + f];
    }
    if (j < end && h == 0) {          // odd remainder on lower half
        const uint32_t w = epack[j];
        const int   s  = (int)(w & 0xFFFFu);
        const float wn = __half2float(__ushort_as_half((uint16_t)(w >> 16)));
        acc += wn * h2[(size_t)s * DO + f];
    }
    acc += __shfl_xor(acc, 32);       // combine the two half-wave partials
    if (lane < 32) {
        const float di = dinv[n];
        out[(size_t)n * DO + f] = acc + h2[(size_t)n * DO + f] * di * di + b2[f];
    }
}

}  // namespace

extern "C" void kernel_launch(void* const* d_in, const int* in_sizes, int n_in,
                              void* d_out, int out_size, void* d_ws, size_t ws_size,
                              hipStream_t stream) {
    const float* x   = (const float*)d_in[0];
    const int*   ei  = (const int*)d_in[1];   // [2,E] int32: row0=src, row1=dst
    const float* W1  = (const float*)d_in[2];
    const float* b1  = (const float*)d_in[3];
    const float* W2  = (const float*)d_in[4];
    const float* b2  = (const float*)d_in[5];
    float* out = (float*)d_out;

    const int* src = ei;
    const int* dst = ei + E;

    // workspace layout (4-byte units), total ~23.2 MB
    char* ws = (char*)d_ws;
    int*      cnt    = (int*)ws;                         // N
    int*      rowptr = cnt + N;                          // N+1
    int*      cursor = rowptr + (N + 1);                 // N
    float*    dinv   = (float*)(cursor + N);             // N
    uint32_t* epack  = (uint32_t*)(dinv + N);            // E
    uint16_t* h1     = (uint16_t*)(epack + E);           // N*64 bf16
    float*    y1     = (float*)(h1 + (size_t)N * DH);    // N*64 f32
    float*    h2     = (float*)h1;                       // N*32 f32, aliases h1 (dead after agg1)

    // 1. zero histogram
    hipLaunchKernelGGL(k_zero, dim3((N + 255) / 256), dim3(256), 0, stream, cnt);
    // 2. in-degree histogram
    hipLaunchKernelGGL(k_count, dim3((E + 255) / 256), dim3(256), 0, stream, dst, cnt);
    // 3. scan -> rowptr/cursor, dinv
    hipLaunchKernelGGL(k_scan, dim3(1), dim3(1024), 0, stream, cnt, rowptr, cursor, dinv);
    // 4. CSR fill (packed src + f16 norm)
    hipLaunchKernelGGL(k_fill, dim3((E + 255) / 256), dim3(256), 0, stream,
                       src, dst, dinv, cursor, epack);
    // 5. h1 = x @ W1  (bf16 out)
    hipLaunchKernelGGL((k_gemm<DH, uint16_t>), dim3((N + 63) / 64), dim3(256), 0, stream,
                       x, W1, h1);
    // 6. y1 = relu(aggregate(h1) + self + b1)
    hipLaunchKernelGGL(k_agg1, dim3((N * 64 + 255) / 256), dim3(256), 0, stream,
                       rowptr, epack, h1, dinv, b1, y1);
    // 7. h2 = y1 @ W2  (f32 out)
    hipLaunchKernelGGL((k_gemm<DO, float>), dim3((N + 63) / 64), dim3(256), 0, stream,
                       y1, W2, h2);
    // 8. out = aggregate(h2) + self + b2
    hipLaunchKernelGGL(k_agg2, dim3((N * 64 + 255) / 256), dim3(256), 0, stream,
                       rowptr, epack, h2, dinv, b2, out);
}

// Round 9
// 231.737 us; speedup vs baseline: 1.6355x; 1.5362x over previous
//
#include <hip/hip_runtime.h>
#include <hip/hip_fp16.h>
#include <cstddef>
#include <cstdint>

namespace {

constexpr int N  = 50000;   // nodes  (must fit u16 for edge packing)
constexpr int E  = 800000;  // edges
constexpr int DH = 64;      // hidden dim
constexpr int DO = 32;      // output dim
constexpr int NB = (N + 255) / 256;   // 196 scan blocks
static_assert(N < 65536, "src packed as u16");
static_assert(NB <= 256, "phase-B single tile");

__device__ inline float bf2f(uint16_t u) {
    union { uint32_t u; float f; } c; c.u = (uint32_t)u << 16; return c.f;
}
__device__ inline uint16_t f2bf(float f) {   // RTNE
    union { float f; uint32_t u; } c; c.f = f;
    uint32_t r = c.u + 0x7FFFu + ((c.u >> 16) & 1u);
    return (uint16_t)(r >> 16);
}

// ---------------------------------------------------------------------------
// zero the dst histogram (ws is poisoned 0xAA; must re-zero every launch)
__global__ void k_zero(int* __restrict__ cnt) {
    int i = blockIdx.x * blockDim.x + threadIdx.x;
    if (i < N) cnt[i] = 0;
}

// in-degree histogram (int atomics)
__global__ void k_count(const int* __restrict__ dst, int* __restrict__ cnt) {
    int e = blockIdx.x * blockDim.x + threadIdx.x;
    if (e < E) atomicAdd(&cnt[dst[e]], 1);
}

// ---------------------------------------------------------------------------
// Device-wide exclusive scan of cnt, 3 phases (the round-7 single-block scan
// was 134 us on one CU; these three touch <=800KB device-wide).
// A: per-block (256-wide) inclusive scan -> incl, block total -> bsum
__global__ void k_scanA(const int* __restrict__ cnt, int* __restrict__ incl,
                        int* __restrict__ bsum) {
    __shared__ int ts[256];
    const int t = threadIdx.x;
    const int i = blockIdx.x * 256 + t;
    const int v = (i < N) ? cnt[i] : 0;
    ts[t] = v;
    __syncthreads();
#pragma unroll
    for (int off = 1; off < 256; off <<= 1) {
        const int u = (t >= off) ? ts[t - off] : 0;
        __syncthreads();
        ts[t] += u;
        __syncthreads();
    }
    if (i < N) incl[i] = ts[t];
    if (t == 255) bsum[blockIdx.x] = ts[255];
}

// B: one block turns bsum into exclusive block bases (in place)
__global__ void k_scanB(int* __restrict__ bsum) {
    __shared__ int ts[256];
    const int t = threadIdx.x;
    const int v = (t < NB) ? bsum[t] : 0;
    ts[t] = v;
    __syncthreads();
#pragma unroll
    for (int off = 1; off < 256; off <<= 1) {
        const int u = (t >= off) ? ts[t - off] : 0;
        __syncthreads();
        ts[t] += u;
        __syncthreads();
    }
    if (t < NB) bsum[t] = ts[t] - v;    // exclusive base for block t
}

// C: rowptr/cursor/dinv from incl + block base
__global__ void k_scanC(const int* __restrict__ cnt, const int* __restrict__ incl,
                        const int* __restrict__ bbase, int* __restrict__ rowptr,
                        int* __restrict__ cursor, float* __restrict__ dinv) {
    const int i = blockIdx.x * 256 + threadIdx.x;
    if (i >= N) return;
    const int c    = cnt[i];
    const int excl = bbase[blockIdx.x] + incl[i] - c;
    rowptr[i] = excl;
    cursor[i] = excl;
    dinv[i]   = rsqrtf((float)(c + 1));
    if (i == N - 1) rowptr[N] = excl + c;   // == E
}

// scatter edges into CSR slots; pack (src u16 | wnorm f16 << 16)
__global__ void k_fill(const int* __restrict__ src, const int* __restrict__ dst,
                       const float* __restrict__ dinv, int* __restrict__ cursor,
                       uint32_t* __restrict__ epack) {
    int e = blockIdx.x * blockDim.x + threadIdx.x;
    if (e >= E) return;
    const int s = src[e], d = dst[e];
    const float wn = dinv[s] * dinv[d];
    const int pos = atomicAdd(&cursor[d], 1);
    const uint16_t hb = __half_as_ushort(__float2half(wn));
    epack[pos] = (uint32_t)s | ((uint32_t)hb << 16);
}

// ---------------------------------------------------------------------------
// H[N,DOUT] = X[N,64] @ W[64,DOUT]; W staged in LDS. OutT = ushort(bf16)|float.
template <int DOUT, typename OutT>
__global__ void k_gemm(const float* __restrict__ X, const float* __restrict__ W,
                       OutT* __restrict__ H) {
    __shared__ float Ws[64 * DOUT];
    const int tid = threadIdx.x;
    for (int i = tid; i < 64 * DOUT; i += 256) Ws[i] = W[i];
    __syncthreads();

    constexpr int RPI = 256 / DOUT;
    const int col  = tid % DOUT;
    const int rsub = tid / DOUT;
    const int rowBase = blockIdx.x * 64;

    for (int r0 = 0; r0 < 64; r0 += RPI) {
        const int row = rowBase + r0 + rsub;
        if (row < N) {
            const float4* xr4 = reinterpret_cast<const float4*>(X + (size_t)row * 64);
            float acc = 0.0f;
#pragma unroll
            for (int k4 = 0; k4 < 16; ++k4) {
                float4 xv = xr4[k4];
                acc += xv.x * Ws[(4 * k4 + 0) * DOUT + col];
                acc += xv.y * Ws[(4 * k4 + 1) * DOUT + col];
                acc += xv.z * Ws[(4 * k4 + 2) * DOUT + col];
                acc += xv.w * Ws[(4 * k4 + 3) * DOUT + col];
            }
            if constexpr (sizeof(OutT) == 2)
                H[(size_t)row * DOUT + col] = f2bf(acc);
            else
                H[(size_t)row * DOUT + col] = acc;
        }
    }
}

// ---------------------------------------------------------------------------
// Layer-1 aggregation, one wave per node, lane = feature (D=64).
__global__ void k_agg1(const int* __restrict__ rowptr, const uint32_t* __restrict__ epack,
                       const uint16_t* __restrict__ h1, const float* __restrict__ dinv,
                       const float* __restrict__ b1, float* __restrict__ y1) {
    const int gtid = blockIdx.x * blockDim.x + threadIdx.x;
    const int n    = gtid >> 6;
    const int lane = gtid & 63;
    if (n >= N) return;
    const int beg = rowptr[n], end = rowptr[n + 1];
    float acc = 0.0f;
#pragma unroll 4
    for (int j = beg; j < end; ++j) {
        const uint32_t w = epack[j];                       // wave-uniform, L1-hot
        const int   s  = (int)(w & 0xFFFFu);
        const float wn = __half2float(__ushort_as_half((uint16_t)(w >> 16)));
        acc += wn * bf2f(h1[(size_t)s * DH + lane]);       // 128B coalesced gather
    }
    const float di   = dinv[n];
    const float self = bf2f(h1[(size_t)n * DH + lane]);
    const float v    = acc + self * di * di + b1[lane];
    y1[(size_t)n * DH + lane] = fmaxf(v, 0.0f);
}

// Layer-2 aggregation, one wave per node, two edges per iteration.
__global__ void k_agg2(const int* __restrict__ rowptr, const uint32_t* __restrict__ epack,
                       const float* __restrict__ h2, const float* __restrict__ dinv,
                       const float* __restrict__ b2, float* __restrict__ out) {
    const int gtid = blockIdx.x * blockDim.x + threadIdx.x;
    const int n    = gtid >> 6;
    const int lane = gtid & 63;
    if (n >= N) return;
    const int h = lane >> 5;          // 0 or 1: which edge of the pair
    const int f = lane & 31;          // feature
    const int beg = rowptr[n], end = rowptr[n + 1];
    float acc = 0.0f;
    int j = beg;
    for (; j + 1 < end; j += 2) {
        const uint32_t w = epack[j + h];
        const int   s  = (int)(w & 0xFFFFu);
        const float wn = __half2float(__ushort_as_half((uint16_t)(w >> 16)));
        acc += wn * h2[(size_t)s * DO + f];
    }
    if (j < end && h == 0) {          // odd remainder on lower half
        const uint32_t w = epack[j];
        const int   s  = (int)(w & 0xFFFFu);
        const float wn = __half2float(__ushort_as_half((uint16_t)(w >> 16)));
        acc += wn * h2[(size_t)s * DO + f];
    }
    acc += __shfl_xor(acc, 32);       // combine the two half-wave partials
    if (lane < 32) {
        const float di = dinv[n];
        out[(size_t)n * DO + f] = acc + h2[(size_t)n * DO + f] * di * di + b2[f];
    }
}

}  // namespace

extern "C" void kernel_launch(void* const* d_in, const int* in_sizes, int n_in,
                              void* d_out, int out_size, void* d_ws, size_t ws_size,
                              hipStream_t stream) {
    const float* x   = (const float*)d_in[0];
    const int*   ei  = (const int*)d_in[1];   // [2,E] int32: row0=src, row1=dst
    const float* W1  = (const float*)d_in[2];
    const float* b1  = (const float*)d_in[3];
    const float* W2  = (const float*)d_in[4];
    const float* b2  = (const float*)d_in[5];
    float* out = (float*)d_out;

    const int* src = ei;
    const int* dst = ei + E;

    // workspace layout (4-byte units), total ~23.5 MB
    char* ws = (char*)d_ws;
    int*      cnt    = (int*)ws;                         // N
    int*      rowptr = cnt + N;                          // N+1
    int*      cursor = rowptr + (N + 1);                 // N
    float*    dinv   = (float*)(cursor + N);             // N
    int*      incl   = (int*)(dinv + N);                 // N   (scan temp)
    int*      bsum   = incl + N;                         // NB  (scan temp)
    uint32_t* epack  = (uint32_t*)(bsum + NB);           // E
    uint16_t* h1     = (uint16_t*)(epack + E);           // N*64 bf16
    float*    y1     = (float*)(h1 + (size_t)N * DH);    // N*64 f32
    float*    h2     = (float*)h1;                       // N*32 f32, aliases h1 (dead after agg1)

    // 1. zero histogram
    hipLaunchKernelGGL(k_zero, dim3((N + 255) / 256), dim3(256), 0, stream, cnt);
    // 2. in-degree histogram
    hipLaunchKernelGGL(k_count, dim3((E + 255) / 256), dim3(256), 0, stream, dst, cnt);
    // 3. device-wide scan -> rowptr/cursor, dinv
    hipLaunchKernelGGL(k_scanA, dim3(NB), dim3(256), 0, stream, cnt, incl, bsum);
    hipLaunchKernelGGL(k_scanB, dim3(1), dim3(256), 0, stream, bsum);
    hipLaunchKernelGGL(k_scanC, dim3(NB), dim3(256), 0, stream, cnt, incl, bsum,
                       rowptr, cursor, dinv);
    // 4. CSR fill (packed src + f16 norm)
    hipLaunchKernelGGL(k_fill, dim3((E + 255) / 256), dim3(256), 0, stream,
                       src, dst, dinv, cursor, epack);
    // 5. h1 = x @ W1  (bf16 out)
    hipLaunchKernelGGL((k_gemm<DH, uint16_t>), dim3((N + 63) / 64), dim3(256), 0, stream,
                       x, W1, h1);
    // 6. y1 = relu(aggregate(h1) + self + b1)
    hipLaunchKernelGGL(k_agg1, dim3((N * 64 + 255) / 256), dim3(256), 0, stream,
                       rowptr, epack, h1, dinv, b1, y1);
    // 7. h2 = y1 @ W2  (f32 out)
    hipLaunchKernelGGL((k_gemm<DO, float>), dim3((N + 63) / 64), dim3(256), 0, stream,
                       y1, W2, h2);
    // 8. out = aggregate(h2) + self + b2
    hipLaunchKernelGGL(k_agg2, dim3((N * 64 + 255) / 256), dim3(256), 0, stream,
                       rowptr, epack, h2, dinv, b2, out);
}

// Round 10
// 203.777 us; speedup vs baseline: 1.8599x; 1.1372x over previous
//
#include <hip/hip_runtime.h>
#include <hip/hip_fp16.h>
#include <cstddef>
#include <cstdint>

namespace {

constexpr int N  = 50000;   // nodes  (must fit u16 for edge packing)
constexpr int E  = 800000;  // edges
constexpr int DH = 64;      // hidden dim
constexpr int DO = 32;      // output dim
constexpr int NB = (N + 255) / 256;   // 196 scan blocks
static_assert(N < 65536, "src packed as u16");
static_assert(NB <= 256, "phase-B single tile");

__device__ inline float bf2f(uint16_t u) {
    union { uint32_t u; float f; } c; c.u = (uint32_t)u << 16; return c.f;
}
__device__ inline uint16_t f2bf(float f) {   // RTNE
    union { float f; uint32_t u; } c; c.f = f;
    uint32_t r = c.u + 0x7FFFu + ((c.u >> 16) & 1u);
    return (uint16_t)(r >> 16);
}
// unpack packed pair of bf16 (low = first in memory)
__device__ inline void bf2x(uint32_t p, float& a, float& b) {
    union { uint32_t u; float f; } c0, c1;
    c0.u = p << 16; c1.u = p & 0xFFFF0000u;
    a = c0.f; b = c1.f;
}

// ---------------------------------------------------------------------------
__global__ void k_zero(int* __restrict__ cnt) {
    int i = blockIdx.x * blockDim.x + threadIdx.x;
    if (i < N) cnt[i] = 0;
}

__global__ void k_count(const int* __restrict__ dst, int* __restrict__ cnt) {
    int e = blockIdx.x * blockDim.x + threadIdx.x;
    if (e < E) atomicAdd(&cnt[dst[e]], 1);
}

// ---------------------------------------------------------------------------
// Device-wide exclusive scan of cnt, 3 phases.
__global__ void k_scanA(const int* __restrict__ cnt, int* __restrict__ incl,
                        int* __restrict__ bsum) {
    __shared__ int ts[256];
    const int t = threadIdx.x;
    const int i = blockIdx.x * 256 + t;
    const int v = (i < N) ? cnt[i] : 0;
    ts[t] = v;
    __syncthreads();
#pragma unroll
    for (int off = 1; off < 256; off <<= 1) {
        const int u = (t >= off) ? ts[t - off] : 0;
        __syncthreads();
        ts[t] += u;
        __syncthreads();
    }
    if (i < N) incl[i] = ts[t];
    if (t == 255) bsum[blockIdx.x] = ts[255];
}

__global__ void k_scanB(int* __restrict__ bsum) {
    __shared__ int ts[256];
    const int t = threadIdx.x;
    const int v = (t < NB) ? bsum[t] : 0;
    ts[t] = v;
    __syncthreads();
#pragma unroll
    for (int off = 1; off < 256; off <<= 1) {
        const int u = (t >= off) ? ts[t - off] : 0;
        __syncthreads();
        ts[t] += u;
        __syncthreads();
    }
    if (t < NB) bsum[t] = ts[t] - v;    // exclusive base for block t
}

__global__ void k_scanC(const int* __restrict__ cnt, const int* __restrict__ incl,
                        const int* __restrict__ bbase, int* __restrict__ rowptr,
                        int* __restrict__ cursor, float* __restrict__ dinv) {
    const int i = blockIdx.x * 256 + threadIdx.x;
    if (i >= N) return;
    const int c    = cnt[i];
    const int excl = bbase[blockIdx.x] + incl[i] - c;
    rowptr[i] = excl;
    cursor[i] = excl;
    dinv[i]   = rsqrtf((float)(c + 1));
    if (i == N - 1) rowptr[N] = excl + c;   // == E
}

// scatter edges into CSR slots; pack (src u16 | wnorm f16 << 16)
__global__ void k_fill(const int* __restrict__ src, const int* __restrict__ dst,
                       const float* __restrict__ dinv, int* __restrict__ cursor,
                       uint32_t* __restrict__ epack) {
    int e = blockIdx.x * blockDim.x + threadIdx.x;
    if (e >= E) return;
    const int s = src[e], d = dst[e];
    const float wn = dinv[s] * dinv[d];
    const int pos = atomicAdd(&cursor[d], 1);
    const uint16_t hb = __half_as_ushort(__float2half(wn));
    epack[pos] = (uint32_t)s | ((uint32_t)hb << 16);
}

// ---------------------------------------------------------------------------
// H[N,DOUT] = X[N,64] @ W[64,DOUT]; W staged in LDS. OutT = ushort(bf16)|float.
template <int DOUT, typename OutT>
__global__ void k_gemm(const float* __restrict__ X, const float* __restrict__ W,
                       OutT* __restrict__ H) {
    __shared__ float Ws[64 * DOUT];
    const int tid = threadIdx.x;
    for (int i = tid; i < 64 * DOUT; i += 256) Ws[i] = W[i];
    __syncthreads();

    constexpr int RPI = 256 / DOUT;
    const int col  = tid % DOUT;
    const int rsub = tid / DOUT;
    const int rowBase = blockIdx.x * 64;

    for (int r0 = 0; r0 < 64; r0 += RPI) {
        const int row = rowBase + r0 + rsub;
        if (row < N) {
            const float4* xr4 = reinterpret_cast<const float4*>(X + (size_t)row * 64);
            float acc = 0.0f;
#pragma unroll
            for (int k4 = 0; k4 < 16; ++k4) {
                float4 xv = xr4[k4];
                acc += xv.x * Ws[(4 * k4 + 0) * DOUT + col];
                acc += xv.y * Ws[(4 * k4 + 1) * DOUT + col];
                acc += xv.z * Ws[(4 * k4 + 2) * DOUT + col];
                acc += xv.w * Ws[(4 * k4 + 3) * DOUT + col];
            }
            if constexpr (sizeof(OutT) == 2)
                H[(size_t)row * DOUT + col] = f2bf(acc);
            else
                H[(size_t)row * DOUT + col] = acc;
        }
    }
}

// ---------------------------------------------------------------------------
// Layer-1 aggregation. One wave per node; 8 groups x 8 lanes.
// Group g handles edge j+g; lane slice sl covers features [sl*8, sl*8+8)
// as one 16B uint4 (8 bf16) load -> 8 rows in flight per load instruction.
__global__ void k_agg1(const int* __restrict__ rowptr, const uint32_t* __restrict__ epack,
                       const uint16_t* __restrict__ h1, const float* __restrict__ dinv,
                       const float* __restrict__ b1, float* __restrict__ y1) {
    const int gtid = blockIdx.x * blockDim.x + threadIdx.x;
    const int n    = gtid >> 6;
    const int lane = gtid & 63;
    if (n >= N) return;
    const int g  = lane >> 3;   // edge slot 0..7
    const int sl = lane & 7;    // 16B feature slice
    const int beg = rowptr[n], end = rowptr[n + 1];

    float acc[8] = {0.f, 0.f, 0.f, 0.f, 0.f, 0.f, 0.f, 0.f};
    for (int j = beg; j < end; j += 8) {
        const int jj = j + g;
        int s = 0; float wn = 0.0f;
        if (jj < end) {
            const uint32_t w = epack[jj];
            s  = (int)(w & 0xFFFFu);
            wn = __half2float(__ushort_as_half((uint16_t)(w >> 16)));
        }
        const uint4 v = *reinterpret_cast<const uint4*>(h1 + (size_t)s * DH + sl * 8);
        float f0, f1;
        bf2x(v.x, f0, f1); acc[0] += wn * f0; acc[1] += wn * f1;
        bf2x(v.y, f0, f1); acc[2] += wn * f0; acc[3] += wn * f1;
        bf2x(v.z, f0, f1); acc[4] += wn * f0; acc[5] += wn * f1;
        bf2x(v.w, f0, f1); acc[6] += wn * f0; acc[7] += wn * f1;
    }
    // combine the 8 edge-groups (lane bits 3..5); afterwards all groups identical
#pragma unroll
    for (int m = 8; m < 64; m <<= 1)
#pragma unroll
        for (int k = 0; k < 8; ++k) acc[k] += __shfl_xor(acc[k], m);

    if (g < 2) {   // 16 lanes write 16B each = full 256B row
        const float di = dinv[n], d2 = di * di;
        const int fb = sl * 8 + g * 4;     // feature base of this lane's float4
        const uint2 sv = *reinterpret_cast<const uint2*>(h1 + (size_t)n * DH + fb);
        float s0, s1, s2, s3;
        bf2x(sv.x, s0, s1); bf2x(sv.y, s2, s3);
        const float4 bv = *reinterpret_cast<const float4*>(b1 + fb);
        float4 o;
        o.x = fmaxf(acc[g * 4 + 0] + s0 * d2 + bv.x, 0.f);
        o.y = fmaxf(acc[g * 4 + 1] + s1 * d2 + bv.y, 0.f);
        o.z = fmaxf(acc[g * 4 + 2] + s2 * d2 + bv.z, 0.f);
        o.w = fmaxf(acc[g * 4 + 3] + s3 * d2 + bv.w, 0.f);
        *reinterpret_cast<float4*>(y1 + (size_t)n * DH + fb) = o;
    }
}

// Layer-2 aggregation, same structure; row = 32 f32 = 8 lanes x float4.
__global__ void k_agg2(const int* __restrict__ rowptr, const uint32_t* __restrict__ epack,
                       const float* __restrict__ h2, const float* __restrict__ dinv,
                       const float* __restrict__ b2, float* __restrict__ out) {
    const int gtid = blockIdx.x * blockDim.x + threadIdx.x;
    const int n    = gtid >> 6;
    const int lane = gtid & 63;
    if (n >= N) return;
    const int g  = lane >> 3;
    const int sl = lane & 7;    // features [sl*4, sl*4+4)
    const int beg = rowptr[n], end = rowptr[n + 1];

    float acc[4] = {0.f, 0.f, 0.f, 0.f};
    for (int j = beg; j < end; j += 8) {
        const int jj = j + g;
        int s = 0; float wn = 0.0f;
        if (jj < end) {
            const uint32_t w = epack[jj];
            s  = (int)(w & 0xFFFFu);
            wn = __half2float(__ushort_as_half((uint16_t)(w >> 16)));
        }
        const float4 v = *reinterpret_cast<const float4*>(h2 + (size_t)s * DO + sl * 4);
        acc[0] += wn * v.x; acc[1] += wn * v.y;
        acc[2] += wn * v.z; acc[3] += wn * v.w;
    }
#pragma unroll
    for (int m = 8; m < 64; m <<= 1)
#pragma unroll
        for (int k = 0; k < 4; ++k) acc[k] += __shfl_xor(acc[k], m);

    if (g == 0) {  // 8 lanes x float4 = full 128B row
        const float di = dinv[n], d2 = di * di;
        const float4 sv = *reinterpret_cast<const float4*>(h2 + (size_t)n * DO + sl * 4);
        const float4 bv = *reinterpret_cast<const float4*>(b2 + sl * 4);
        float4 o;
        o.x = acc[0] + sv.x * d2 + bv.x;
        o.y = acc[1] + sv.y * d2 + bv.y;
        o.z = acc[2] + sv.z * d2 + bv.z;
        o.w = acc[3] + sv.w * d2 + bv.w;
        *reinterpret_cast<float4*>(out + (size_t)n * DO + sl * 4) = o;
    }
}

// 64B-align each ws sub-buffer (16B vector loads require it)
template <typename T>
T* alignp(char*& p, size_t count) {
    uintptr_t u = ((uintptr_t)p + 63) & ~(uintptr_t)63;
    p = (char*)(u + count * sizeof(T));
    return (T*)u;
}

}  // namespace

extern "C" void kernel_launch(void* const* d_in, const int* in_sizes, int n_in,
                              void* d_out, int out_size, void* d_ws, size_t ws_size,
                              hipStream_t stream) {
    const float* x   = (const float*)d_in[0];
    const int*   ei  = (const int*)d_in[1];   // [2,E] int32: row0=src, row1=dst
    const float* W1  = (const float*)d_in[2];
    const float* b1  = (const float*)d_in[3];
    const float* W2  = (const float*)d_in[4];
    const float* b2  = (const float*)d_in[5];
    float* out = (float*)d_out;

    const int* src = ei;
    const int* dst = ei + E;

    // workspace layout, each 64B-aligned; total ~23.6 MB
    char* p = (char*)d_ws;
    int*      cnt    = alignp<int>(p, N);
    int*      rowptr = alignp<int>(p, N + 1);
    int*      cursor = alignp<int>(p, N);
    float*    dinv   = alignp<float>(p, N);
    int*      incl   = alignp<int>(p, N);
    int*      bsum   = alignp<int>(p, NB);
    uint32_t* epack  = alignp<uint32_t>(p, E);
    uint16_t* h1     = alignp<uint16_t>(p, (size_t)N * DH);   // bf16
    float*    y1     = alignp<float>(p, (size_t)N * DH);
    float*    h2     = (float*)h1;    // aliases h1 (dead after agg1); 64B-aligned

    // 1. zero histogram
    hipLaunchKernelGGL(k_zero, dim3((N + 255) / 256), dim3(256), 0, stream, cnt);
    // 2. in-degree histogram
    hipLaunchKernelGGL(k_count, dim3((E + 255) / 256), dim3(256), 0, stream, dst, cnt);
    // 3. device-wide scan -> rowptr/cursor, dinv
    hipLaunchKernelGGL(k_scanA, dim3(NB), dim3(256), 0, stream, cnt, incl, bsum);
    hipLaunchKernelGGL(k_scanB, dim3(1), dim3(256), 0, stream, bsum);
    hipLaunchKernelGGL(k_scanC, dim3(NB), dim3(256), 0, stream, cnt, incl, bsum,
                       rowptr, cursor, dinv);
    // 4. CSR fill (packed src + f16 norm)
    hipLaunchKernelGGL(k_fill, dim3((E + 255) / 256), dim3(256), 0, stream,
                       src, dst, dinv, cursor, epack);
    // 5. h1 = x @ W1  (bf16 out)
    hipLaunchKernelGGL((k_gemm<DH, uint16_t>), dim3((N + 63) / 64), dim3(256), 0, stream,
                       x, W1, h1);
    // 6. y1 = relu(aggregate(h1) + self + b1)
    hipLaunchKernelGGL(k_agg1, dim3((N * 64 + 255) / 256), dim3(256), 0, stream,
                       rowptr, epack, h1, dinv, b1, y1);
    // 7. h2 = y1 @ W2  (f32 out)
    hipLaunchKernelGGL((k_gemm<DO, float>), dim3((N + 63) / 64), dim3(256), 0, stream,
                       y1, W2, h2);
    // 8. out = aggregate(h2) + self + b2
    hipLaunchKernelGGL(k_agg2, dim3((N * 64 + 255) / 256), dim3(256), 0, stream,
                       rowptr, epack, h2, dinv, b2, out);
}